// Round 19
// baseline (193.566 us; speedup 1.0000x reference)
//
#include <hip/hip_runtime.h>
#include <hip/hip_bf16.h>

#define BATCH 64
#define MDIM 512
#define NDIM 1024
#define KDIM 1024

#define BM 256
#define BN 128
#define BK 64
#define NKT (KDIM / BK)     // 16 K-tiles

typedef __attribute__((ext_vector_type(4))) float f32x4;
typedef __attribute__((ext_vector_type(8))) short bf16x8;
typedef __attribute__((ext_vector_type(4))) unsigned int u32x4;

__device__ __forceinline__ unsigned int cvt2(float lo, float hi) {
    __hip_bfloat162 h = __float22bfloat162_rn(float2{lo, hi});
    return *(unsigned int*)&h;
}

#define MFMA16(a, b, c) __builtin_amdgcn_mfma_f32_16x16x32_bf16((a), (b), (c), 0, 0, 0)
#define SB0 __builtin_amdgcn_sched_barrier(0)
#define WAITLG(n) do { asm volatile("s_waitcnt lgkmcnt(" #n ")" ::: "memory"); SB0; } while (0)
#define BAR do { SB0; __builtin_amdgcn_s_barrier(); SB0; } while (0)

// Producer-consumer wave specialization: waves 0-3 = consumers (pure
// ds_read+MFMA), waves 4-7 = producers (pure load+cvt+ds_write). The
// barrier rhythm is identical on both paths (1 prologue + NKT in-loop).
__global__ __launch_bounds__(512, 2)
void grouped_fc_kernel(const float* __restrict__ X,
                       const float* __restrict__ W,
                       const float* __restrict__ Bias,
                       float* __restrict__ Out) {
    // XCD swizzle (bijective: 1024 % 8 == 0): XCD j gets batches [8j,8j+8)
    const int swz  = (blockIdx.x & 7) * 128 + (blockIdx.x >> 3);
    const int bidx = swz >> 4;      // 0..63 batch
    const int tile = swz & 15;      // 2 M-tiles x 8 N-tiles
    const int tm = tile & 1;
    const int tn = tile >> 1;       // 0..7

    const int tid  = threadIdx.x;
    const int lane = tid & 63;
    const int wid  = tid >> 6;

    // bf16 [row][64], 8 x 16B slots/row, slot s stored at s ^ (row&7).
    // Both producer writes (8 lanes per slot-position) and consumer reads
    // (8 lanes per slot-position) uniform -> 0 conflicts (R9/R13-measured).
    __shared__ unsigned short ldsA[2][BM][BK];   // 64 KB
    __shared__ unsigned short ldsB[2][BN][BK];   // 32 KB

    const float* srcA = X + ((size_t)bidx * MDIM + (size_t)tm * BM) * KDIM;
    const float* srcB = W + ((size_t)bidx * NDIM + (size_t)tn * BN) * KDIM;

    if (wid < 4) {
        // ================= CONSUMER =================
        const int wm = wid & 1;          // 2 wave rows (128 out-rows)
        const int wn = wid >> 1;         // 2 wave cols (64 out-cols)
        const int frow = lane & 15;
        const int khi  = lane >> 4;
        const int xr   = frow & 7;
        const int oK0  = ((khi)     ^ xr) * 8;
        const int oK1  = ((4 + khi) ^ xr) * 8;

        f32x4 acc[8][4];
#pragma unroll
        for (int mi = 0; mi < 8; ++mi)
#pragma unroll
            for (int ni = 0; ni < 4; ++ni)
                acc[mi][ni] = (f32x4){0.f, 0.f, 0.f, 0.f};

        BAR;                             // tile 0 sealed by producers

        bf16x8 af[8], bfr[4];
#pragma unroll 1
        for (int kt = 0; kt < NKT; ++kt) {
            const int rd = kt & 1;
            // ks0
#pragma unroll
            for (int mi = 0; mi < 8; ++mi)
                af[mi] = *(const bf16x8*)&ldsA[rd][wm * 128 + mi * 16 + frow][oK0];
#pragma unroll
            for (int ni = 0; ni < 4; ++ni)
                bfr[ni] = *(const bf16x8*)&ldsB[rd][wn * 64 + ni * 16 + frow][oK0];
            WAITLG(0);
            __builtin_amdgcn_s_setprio(1);
#pragma unroll
            for (int mi = 0; mi < 8; ++mi)
#pragma unroll
                for (int ni = 0; ni < 4; ++ni)
                    acc[mi][ni] = MFMA16(af[mi], bfr[ni], acc[mi][ni]);
            __builtin_amdgcn_s_setprio(0);
            SB0;
            // ks1
#pragma unroll
            for (int mi = 0; mi < 8; ++mi)
                af[mi] = *(const bf16x8*)&ldsA[rd][wm * 128 + mi * 16 + frow][oK1];
#pragma unroll
            for (int ni = 0; ni < 4; ++ni)
                bfr[ni] = *(const bf16x8*)&ldsB[rd][wn * 64 + ni * 16 + frow][oK1];
            WAITLG(0);
            __builtin_amdgcn_s_setprio(1);
#pragma unroll
            for (int mi = 0; mi < 8; ++mi)
#pragma unroll
                for (int ni = 0; ni < 4; ++ni)
                    acc[mi][ni] = MFMA16(af[mi], bfr[ni], acc[mi][ni]);
            __builtin_amdgcn_s_setprio(0);
            BAR;                         // seals buf^1 (producers drained)
        }

        // epilogue: acc layout col=lane&15, row=(lane>>4)*4+r (m89-verified)
#pragma unroll
        for (int ni = 0; ni < 4; ++ni) {
            const int gc = tn * BN + wn * 64 + ni * 16 + frow;
            const float bv = Bias[bidx * NDIM + gc];
#pragma unroll
            for (int mi = 0; mi < 8; ++mi) {
                const int gr0 = tm * BM + wm * 128 + mi * 16 + khi * 4;
                float* po = Out + ((size_t)bidx * MDIM + gr0) * NDIM + gc;
#pragma unroll
                for (int r = 0; r < 4; ++r)
                    po[(size_t)r * NDIM] = acc[mi][ni][r] + bv;
            }
        }
    } else {
        // ================= PRODUCER =================
        // 256 producer threads stage A(256x64) + B(128x64) fp32 -> bf16.
        // Unit = 8 fp32 of one row; 384 rows x 8 units = 3072 units;
        // unit flat = u*256 + t: u 0..7 -> A, u 8..11 -> B.
        const int t = tid & 255;
        const int rsub = t >> 3;         // row-in-32-chunk
        const int cg   = t & 7;          // col-group (8 fp32)

        f32x4 pr[12][2];                 // 96 VGPR staging

        auto STAGE = [&](int buf, int kt) {
            // issue all 24 loads
#pragma unroll
            for (int u = 0; u < 8; ++u) {
                const int row = u * 32 + rsub;
                const float* p = srcA + (size_t)row * KDIM + kt * BK + cg * 8;
                pr[u][0] = *(const f32x4*)(p);
                pr[u][1] = *(const f32x4*)(p + 4);
            }
#pragma unroll
            for (int u = 8; u < 12; ++u) {
                const int row = (u - 8) * 32 + rsub;
                const float* p = srcB + (size_t)row * KDIM + kt * BK + cg * 8;
                pr[u][0] = *(const f32x4*)(p);
                pr[u][1] = *(const f32x4*)(p + 4);
            }
            // cvt + swizzled writes (vmcnt waits via reg deps, pipelined)
#pragma unroll
            for (int u = 0; u < 8; ++u) {
                const int row = u * 32 + rsub;
                u32x4 w;
                w[0] = cvt2(pr[u][0][0], pr[u][0][1]);
                w[1] = cvt2(pr[u][0][2], pr[u][0][3]);
                w[2] = cvt2(pr[u][1][0], pr[u][1][1]);
                w[3] = cvt2(pr[u][1][2], pr[u][1][3]);
                *(u32x4*)&ldsA[buf][row][(cg ^ (row & 7)) * 8] = w;
            }
#pragma unroll
            for (int u = 8; u < 12; ++u) {
                const int row = (u - 8) * 32 + rsub;
                u32x4 w;
                w[0] = cvt2(pr[u][0][0], pr[u][0][1]);
                w[1] = cvt2(pr[u][0][2], pr[u][0][3]);
                w[2] = cvt2(pr[u][1][0], pr[u][1][1]);
                w[3] = cvt2(pr[u][1][2], pr[u][1][3]);
                *(u32x4*)&ldsB[buf][row][(cg ^ (row & 7)) * 8] = w;
            }
        };

        // prologue: stage tile 0 -> buf0, seal
        STAGE(0, 0);
        WAITLG(0);
        BAR;

#pragma unroll 1
        for (int kt = 0; kt < NKT; ++kt) {
            if (kt + 1 < NKT) STAGE((kt & 1) ^ 1, kt + 1);
            WAITLG(0);                   // writes drained (release edge)
            BAR;                         // matches consumer tile-end BAR
        }
    }
}

extern "C" void kernel_launch(void* const* d_in, const int* in_sizes, int n_in,
                              void* d_out, int out_size, void* d_ws, size_t ws_size,
                              hipStream_t stream) {
    const float* X  = (const float*)d_in[0];
    const float* W  = (const float*)d_in[1];
    const float* Bs = (const float*)d_in[2];
    float* Out = (float*)d_out;

    grouped_fc_kernel<<<dim3(1024), dim3(512), 0, stream>>>(X, W, Bs, Out);
}

// Round 20
// 139.353 us; speedup vs baseline: 1.3890x; 1.3890x over previous
//
#include <hip/hip_runtime.h>
#include <hip/hip_bf16.h>

#define BATCH 64
#define MDIM 512
#define NDIM 1024
#define KDIM 1024

#define BM 256
#define BN 256
#define BK 64
#define NKT (KDIM / BK)     // 16 K-tiles

typedef __attribute__((ext_vector_type(4))) float f32x4;
typedef __attribute__((ext_vector_type(16))) float f32x16;
typedef __attribute__((ext_vector_type(8))) short bf16x8;
typedef __attribute__((ext_vector_type(4))) unsigned int u32x4;

__device__ __forceinline__ unsigned int cvt2(float lo, float hi) {
    __hip_bfloat162 h = __float22bfloat162_rn(float2{lo, hi});
    return *(unsigned int*)&h;
}

#define MFMA32(a, b, c) __builtin_amdgcn_mfma_f32_32x32x16_bf16((a), (b), (c), 0, 0, 0)
#define SB0 __builtin_amdgcn_sched_barrier(0)
#define WAITLG(n) do { asm volatile("s_waitcnt lgkmcnt(" #n ")" ::: "memory"); SB0; } while (0)
#define BAR do { SB0; __builtin_amdgcn_s_barrier(); SB0; } while (0)

__global__ __launch_bounds__(512, 2)
void grouped_fc_kernel(const float* __restrict__ X,
                       const float* __restrict__ W,
                       const float* __restrict__ Bias,
                       float* __restrict__ Out) {
    // XCD swizzle (bijective: 512 % 8 == 0)
    const int swz  = (blockIdx.x & 7) * 64 + (blockIdx.x >> 3);
    const int bidx = swz >> 3;
    const int tile = swz & 7;
    const int tm = tile & 1;
    const int tn = tile >> 1;

    const int tid  = threadIdx.x;
    const int lane = tid & 63;
    const int wid  = tid >> 6;
    const int wm   = wid & 1;      // 2 wave rows (128 out-rows)
    const int wn   = wid >> 1;     // 4 wave cols (64 out-cols)

    // [row][64] bf16 = 8 x 16B slots/row; slot s at s ^ (row&7).
    // R9/R13-measured: SQ_LDS_BANK_CONFLICT == 0 (reads AND writes uniform
    // 8 lanes per 16B granule; re-derived below for the 32x32 frag reads).
    __shared__ unsigned short ldsA[2][BM][BK];
    __shared__ unsigned short ldsB[2][BN][BK];

    const float* srcA = X + ((size_t)bidx * MDIM + (size_t)tm * BM) * KDIM;
    const float* srcB = W + ((size_t)bidx * NDIM + (size_t)tn * BN) * KDIM;

    // staging: 4 threads/row, 16 fp32 each, per 128-row half-tile (as R13)
    const int s_r  = tid >> 2;
    const int s_cf = (tid & 3) * 16;
    const int s_x  = s_r & 7;
    const int so0  = (((tid & 3) * 2)     ^ s_x) * 8;
    const int so1  = (((tid & 3) * 2 + 1) ^ s_x) * 8;

    f32x4 st0[4], st1[4];

    auto ISSUE = [&](const float* srcbase, int hv, int kt_, f32x4 (&s)[4]) {
        const float* p = srcbase + (size_t)(hv * 128 + s_r) * KDIM + kt_ * BK + s_cf;
#pragma unroll
        for (int v = 0; v < 4; ++v) s[v] = *(const f32x4*)(p + v * 4);
    };

    auto CVTW = [&](unsigned short* ldsbase, int hv, f32x4 (&s)[4]) {
        const int row = hv * 128 + s_r;
        u32x4 w0, w1;
        w0[0] = cvt2(s[0][0], s[0][1]); w0[1] = cvt2(s[0][2], s[0][3]);
        w0[2] = cvt2(s[1][0], s[1][1]); w0[3] = cvt2(s[1][2], s[1][3]);
        w1[0] = cvt2(s[2][0], s[2][1]); w1[1] = cvt2(s[2][2], s[2][3]);
        w1[2] = cvt2(s[3][0], s[3][1]); w1[3] = cvt2(s[3][2], s[3][3]);
        *(u32x4*)&ldsbase[(size_t)row * BK + so0] = w0;
        *(u32x4*)&ldsbase[(size_t)row * BK + so1] = w1;
    };

    // 32x32x16 fragment addressing: lane holds row/col (lane&31), k-group
    // (lane>>5); K-step s covers k [16s,16s+16) -> this lane's 8 bf16 at
    // slot 2s+kg, stored at (2s+kg)^(row&7). Frag base rows are multiples
    // of 32 so row&7 == (lane&31)&7.
    const int arow = lane & 31;
    const int kg   = lane >> 5;
    const int xr   = arow & 7;
    int oS[4];
#pragma unroll
    for (int s = 0; s < 4; ++s) oS[s] = ((2 * s + kg) ^ xr) * 8;

    auto rdA = [&](int buf, int mi, int o) {
        return *(const bf16x8*)&ldsA[buf][wm * 128 + mi * 32 + arow][o];
    };
    auto rdB = [&](int buf, int ni, int o) {
        return *(const bf16x8*)&ldsB[buf][wn * 64 + ni * 32 + arow][o];
    };

    f32x16 acc[4][2];
#pragma unroll
    for (int mi = 0; mi < 4; ++mi)
#pragma unroll
        for (int ni = 0; ni < 2; ++ni)
#pragma unroll
            for (int r = 0; r < 16; ++r)
                acc[mi][ni][r] = 0.f;

    // ---- prologue: stage tile 0 -> buf0; issue tile-1 A halves ----
    ISSUE(srcA, 0, 0, st0); ISSUE(srcA, 1, 0, st1);
    CVTW(&ldsA[0][0][0], 0, st0); CVTW(&ldsA[0][0][0], 1, st1);
    ISSUE(srcB, 0, 0, st0); ISSUE(srcB, 1, 0, st1);
    CVTW(&ldsB[0][0][0], 0, st0); CVTW(&ldsB[0][0][0], 1, st1);
    ISSUE(srcA, 0, 1, st0); ISSUE(srcA, 1, 1, st1);
    WAITLG(0);
    BAR;

    bf16x8 af[4], bfr[2];

    // main loop (R13 schedule, 4 phases/tile, one barrier each; counted
    // lgkm waits leave only the newest ds_writes pending).
#pragma unroll 1
    for (int kt = 0; kt < NKT - 1; ++kt) {
        const int rd = kt & 1;
        const bool m2 = (kt + 2 < NKT);
        unsigned short* nA = &ldsA[rd ^ 1][0][0];
        unsigned short* nB = &ldsB[rd ^ 1][0][0];

        // ---- P0: step0 reads (queue empty -> wait 0) ----
#pragma unroll
        for (int mi = 0; mi < 4; ++mi) af[mi] = rdA(rd, mi, oS[0]);
        bfr[0] = rdB(rd, 0, oS[0]); bfr[1] = rdB(rd, 1, oS[0]);
        WAITLG(0);
        __builtin_amdgcn_s_setprio(1);
#pragma unroll
        for (int mi = 0; mi < 4; ++mi) {
            acc[mi][0] = MFMA32(af[mi], bfr[0], acc[mi][0]);
            acc[mi][1] = MFMA32(af[mi], bfr[1], acc[mi][1]);
        }
        __builtin_amdgcn_s_setprio(0);
        SB0;
#pragma unroll
        for (int mi = 0; mi < 4; ++mi) af[mi] = rdA(rd, mi, oS[1]);  // 4r
        bfr[0] = rdB(rd, 0, oS[1]); bfr[1] = rdB(rd, 1, oS[1]);      // 2r
        CVTW(nA, 0, st0);                                            // 2w
        ISSUE(srcB, 0, kt + 1, st0);
        BAR;

        // ---- P1: queue [6r, 2w] -> wait 2 ----
        WAITLG(2);
        __builtin_amdgcn_s_setprio(1);
#pragma unroll
        for (int mi = 0; mi < 4; ++mi) {
            acc[mi][0] = MFMA32(af[mi], bfr[0], acc[mi][0]);
            acc[mi][1] = MFMA32(af[mi], bfr[1], acc[mi][1]);
        }
        __builtin_amdgcn_s_setprio(0);
        SB0;
#pragma unroll
        for (int mi = 0; mi < 4; ++mi) af[mi] = rdA(rd, mi, oS[2]);
        bfr[0] = rdB(rd, 0, oS[2]); bfr[1] = rdB(rd, 1, oS[2]);
        CVTW(nA, 1, st1);
        ISSUE(srcB, 1, kt + 1, st1);
        BAR;

        // ---- P2: queue [2w, 6r, 2w] -> wait 2 ----
        WAITLG(2);
        __builtin_amdgcn_s_setprio(1);
#pragma unroll
        for (int mi = 0; mi < 4; ++mi) {
            acc[mi][0] = MFMA32(af[mi], bfr[0], acc[mi][0]);
            acc[mi][1] = MFMA32(af[mi], bfr[1], acc[mi][1]);
        }
        __builtin_amdgcn_s_setprio(0);
        SB0;
#pragma unroll
        for (int mi = 0; mi < 4; ++mi) af[mi] = rdA(rd, mi, oS[3]);
        bfr[0] = rdB(rd, 0, oS[3]); bfr[1] = rdB(rd, 1, oS[3]);
        CVTW(nB, 0, st0);
        if (m2) ISSUE(srcA, 0, kt + 2, st0);
        BAR;

        // ---- P3: queue [2w, 6r, 2w] -> wait 2 ----
        WAITLG(2);
        __builtin_amdgcn_s_setprio(1);
#pragma unroll
        for (int mi = 0; mi < 4; ++mi) {
            acc[mi][0] = MFMA32(af[mi], bfr[0], acc[mi][0]);
            acc[mi][1] = MFMA32(af[mi], bfr[1], acc[mi][1]);
        }
        __builtin_amdgcn_s_setprio(0);
        SB0;
        CVTW(nB, 1, st1);
        if (m2) ISSUE(srcA, 1, kt + 2, st1);
        WAITLG(0);                       // tile seal drain
        BAR;                             // buf^1 sealed
    }

    // ---- peeled last tile ----
    {
        const int rd = (NKT - 1) & 1;
#pragma unroll
        for (int s = 0; s < 4; ++s) {
#pragma unroll
            for (int mi = 0; mi < 4; ++mi) af[mi] = rdA(rd, mi, oS[s]);
            bfr[0] = rdB(rd, 0, oS[s]); bfr[1] = rdB(rd, 1, oS[s]);
            WAITLG(0);
#pragma unroll
            for (int mi = 0; mi < 4; ++mi) {
                acc[mi][0] = MFMA32(af[mi], bfr[0], acc[mi][0]);
                acc[mi][1] = MFMA32(af[mi], bfr[1], acc[mi][1]);
            }
        }
    }

    // epilogue: 32x32 C/D layout col=lane&31, row=(reg&3)+8*(reg>>2)+4*kg
    // (m74/m101-verified)
#pragma unroll
    for (int ni = 0; ni < 2; ++ni) {
        const int gc = tn * BN + wn * 64 + ni * 32 + arow;
        const float bv = Bias[bidx * NDIM + gc];
#pragma unroll
        for (int mi = 0; mi < 4; ++mi) {
            const int rbase = tm * BM + wm * 128 + mi * 32 + 4 * kg;
            float* po = Out + ((size_t)bidx * MDIM + rbase) * NDIM + gc;
#pragma unroll
            for (int r = 0; r < 16; ++r) {
                const int rr = (r & 3) + 8 * (r >> 2);
                po[(size_t)rr * NDIM] = acc[mi][ni][r] + bv;
            }
        }
    }
}

extern "C" void kernel_launch(void* const* d_in, const int* in_sizes, int n_in,
                              void* d_out, int out_size, void* d_ws, size_t ws_size,
                              hipStream_t stream) {
    const float* X  = (const float*)d_in[0];
    const float* W  = (const float*)d_in[1];
    const float* Bs = (const float*)d_in[2];
    float* Out = (float*)d_out;

    grouped_fc_kernel<<<dim3(512), dim3(512), 0, stream>>>(X, W, Bs, Out);
}

// Round 21
// 136.979 us; speedup vs baseline: 1.4131x; 1.0173x over previous
//
#include <hip/hip_runtime.h>
#include <hip/hip_bf16.h>

#define BATCH 64
#define MDIM 512
#define NDIM 1024
#define KDIM 1024

#define BM 256
#define BN 256
#define BK 64
#define NKT (KDIM / BK)     // 16 K-tiles

typedef __attribute__((ext_vector_type(4))) float f32x4;
typedef __attribute__((ext_vector_type(8))) short bf16x8;
typedef __attribute__((ext_vector_type(4))) unsigned int u32x4;

__device__ __forceinline__ unsigned int cvt2(float lo, float hi) {
    __hip_bfloat162 h = __float22bfloat162_rn(float2{lo, hi});
    return *(unsigned int*)&h;
}

#define MFMA16(a, b, c) __builtin_amdgcn_mfma_f32_16x16x32_bf16((a), (b), (c), 0, 0, 0)
#define SB0 __builtin_amdgcn_sched_barrier(0)
// counted lgkm wait; SB0 after is rule-18 correctness (hipcc hoists
// register-only MFMA past inline-asm waitcnt otherwise).
#define WAITLG(n) do { asm volatile("s_waitcnt lgkmcnt(" #n ")" ::: "memory"); SB0; } while (0)
#define BAR do { SB0; __builtin_amdgcn_s_barrier(); SB0; } while (0)

__global__ __launch_bounds__(512, 2)
void grouped_fc_kernel(const float* __restrict__ X,
                       const float* __restrict__ W,
                       const float* __restrict__ Bias,
                       float* __restrict__ Out) {
    // XCD swizzle (bijective: 512 % 8 == 0)
    const int swz  = (blockIdx.x & 7) * 64 + (blockIdx.x >> 3);
    const int bidx = swz >> 3;
    const int tile = swz & 7;
    const int tm = tile & 1;
    const int tn = tile >> 1;

    const int tid  = threadIdx.x;
    const int lane = tid & 63;
    const int wid  = tid >> 6;
    const int wm   = wid & 1;      // 2 wave rows (128 out-rows)
    const int wn   = wid >> 1;     // 4 wave cols (64 out-cols)

    // [row][64] bf16 = 8 x 16B slots/row; slot s at s ^ (row&7).
    // R9/R13-measured: SQ_LDS_BANK_CONFLICT == 0.
    __shared__ unsigned short ldsA[2][BM][BK];
    __shared__ unsigned short ldsB[2][BN][BK];

    const float* srcA = X + ((size_t)bidx * MDIM + (size_t)tm * BM) * KDIM;
    const float* srcB = W + ((size_t)bidx * NDIM + (size_t)tn * BN) * KDIM;

    // staging: 4 threads/row, 16 fp32 each, per 128-row half-tile
    const int s_r  = tid >> 2;
    const int s_cf = (tid & 3) * 16;
    const int s_x  = s_r & 7;
    const int so0  = (((tid & 3) * 2)     ^ s_x) * 8;
    const int so1  = (((tid & 3) * 2 + 1) ^ s_x) * 8;

    f32x4 st0[4], st1[4];

    auto ISSUE = [&](const float* srcbase, int hv, int kt_, f32x4 (&s)[4]) {
        const float* p = srcbase + (size_t)(hv * 128 + s_r) * KDIM + kt_ * BK + s_cf;
#pragma unroll
        for (int v = 0; v < 4; ++v) s[v] = *(const f32x4*)(p + v * 4);
    };

    auto CVTW = [&](unsigned short* ldsbase, int hv, f32x4 (&s)[4]) {
        const int row = hv * 128 + s_r;
        u32x4 w0, w1;
        w0[0] = cvt2(s[0][0], s[0][1]); w0[1] = cvt2(s[0][2], s[0][3]);
        w0[2] = cvt2(s[1][0], s[1][1]); w0[3] = cvt2(s[1][2], s[1][3]);
        w1[0] = cvt2(s[2][0], s[2][1]); w1[1] = cvt2(s[2][2], s[2][3]);
        w1[2] = cvt2(s[3][0], s[3][1]); w1[3] = cvt2(s[3][2], s[3][3]);
        *(u32x4*)&ldsbase[(size_t)row * BK + so0] = w0;
        *(u32x4*)&ldsbase[(size_t)row * BK + so1] = w1;
    };

    // frag reads: row&7 == frow&7 (frag base rows are multiples of 8)
    const int frow = lane & 15;
    const int khi  = lane >> 4;
    const int xr   = frow & 7;
    const int oK0  = ((khi)     ^ xr) * 8;
    const int oK1  = ((4 + khi) ^ xr) * 8;

    auto rdA = [&](int buf, int mi, int o) {
        return *(const bf16x8*)&ldsA[buf][wm * 128 + mi * 16 + frow][o];
    };
    auto rdB = [&](int buf, int ni, int o) {
        return *(const bf16x8*)&ldsB[buf][wn * 64 + ni * 16 + frow][o];
    };

    f32x4 acc[8][4];
#pragma unroll
    for (int mi = 0; mi < 8; ++mi)
#pragma unroll
        for (int ni = 0; ni < 4; ++ni)
            acc[mi][ni] = (f32x4){0.f, 0.f, 0.f, 0.f};

    // ---- prologue: stage tile 0 -> buf0; issue tile-1 A halves ----
    ISSUE(srcA, 0, 0, st0); ISSUE(srcA, 1, 0, st1);
    CVTW(&ldsA[0][0][0], 0, st0); CVTW(&ldsA[0][0][0], 1, st1);
    ISSUE(srcB, 0, 0, st0); ISSUE(srcB, 1, 0, st1);
    CVTW(&ldsB[0][0][0], 0, st0); CVTW(&ldsB[0][0][0], 1, st1);
    ISSUE(srcA, 0, 1, st0); ISSUE(srcA, 1, 1, st1);
    WAITLG(0);
    BAR;

    bf16x8 af[8], bfr[4];

    // main loop: tiles 0..NKT-2, 4 phases/tile, one barrier each.
    // MFMA clusters may interleave with the following read burst (no fence
    // between them); one SB0 pins reads-before-writes so counted waits are
    // exact. All B-writes consolidated in P2 -> P3 is write-free and the
    // tile-seal drain has a full phase of slack.
#pragma unroll 1
    for (int kt = 0; kt < NKT - 1; ++kt) {
        const int rd = kt & 1;
        const bool m2 = (kt + 2 < NKT);
        unsigned short* nA = &ldsA[rd ^ 1][0][0];
        unsigned short* nB = &ldsB[rd ^ 1][0][0];

        // ---- P0: [10r] wait0 | MFMA{0,1} || 2r ; SB0 ; 2w + ISSUE ----
#pragma unroll
        for (int mi = 0; mi < 8; ++mi) af[mi] = rdA(rd, mi, oK0);
        bfr[0] = rdB(rd, 0, oK0); bfr[1] = rdB(rd, 1, oK0);
        WAITLG(0);
        __builtin_amdgcn_s_setprio(1);
#pragma unroll
        for (int mi = 0; mi < 8; ++mi) {
            acc[mi][0] = MFMA16(af[mi], bfr[0], acc[mi][0]);
            acc[mi][1] = MFMA16(af[mi], bfr[1], acc[mi][1]);
        }
        __builtin_amdgcn_s_setprio(0);
        bfr[2] = rdB(rd, 2, oK0); bfr[3] = rdB(rd, 3, oK0);   // 2 reads
        SB0;                                                   // r-before-w
        CVTW(nA, 0, st0);                                      // 2 writes
        ISSUE(srcB, 0, kt + 1, st0);
        BAR;

        // ---- P1: queue [2r,2w] wait2 | MFMA{2,3} || 10r ; SB0 ; 2w ----
        WAITLG(2);
        __builtin_amdgcn_s_setprio(1);
#pragma unroll
        for (int mi = 0; mi < 8; ++mi) {
            acc[mi][2] = MFMA16(af[mi], bfr[2], acc[mi][2]);
            acc[mi][3] = MFMA16(af[mi], bfr[3], acc[mi][3]);
        }
        __builtin_amdgcn_s_setprio(0);
#pragma unroll
        for (int mi = 0; mi < 8; ++mi) af[mi] = rdA(rd, mi, oK1);  // 8 reads
        bfr[0] = rdB(rd, 0, oK1); bfr[1] = rdB(rd, 1, oK1);        // 2 reads
        SB0;
        CVTW(nA, 1, st1);                                          // 2 writes
        ISSUE(srcB, 1, kt + 1, st1);
        BAR;

        // ---- P2: queue [2w,10r,2w] wait2 | MFMA{0,1} || 2r ; SB0 ; 4w ----
        WAITLG(2);
        __builtin_amdgcn_s_setprio(1);
#pragma unroll
        for (int mi = 0; mi < 8; ++mi) {
            acc[mi][0] = MFMA16(af[mi], bfr[0], acc[mi][0]);
            acc[mi][1] = MFMA16(af[mi], bfr[1], acc[mi][1]);
        }
        __builtin_amdgcn_s_setprio(0);
        bfr[2] = rdB(rd, 2, oK1); bfr[3] = rdB(rd, 3, oK1);   // 2 reads
        SB0;
        CVTW(nB, 0, st0); CVTW(nB, 1, st1);                    // 4 writes
        if (m2) ISSUE(srcA, 0, kt + 2, st0);
        BAR;

        // ---- P3: queue [2w,2r,4w] wait4 | MFMA{2,3} ; seal (1-phase slack) ----
        WAITLG(4);
        __builtin_amdgcn_s_setprio(1);
#pragma unroll
        for (int mi = 0; mi < 8; ++mi) {
            acc[mi][2] = MFMA16(af[mi], bfr[2], acc[mi][2]);
            acc[mi][3] = MFMA16(af[mi], bfr[3], acc[mi][3]);
        }
        __builtin_amdgcn_s_setprio(0);
        if (m2) ISSUE(srcA, 1, kt + 2, st1);
        WAITLG(0);                       // drains P2's writes (~1 phase old)
        BAR;                             // buf^1 sealed
    }

    // ---- peeled last tile (no staging) ----
    {
        const int rd = (NKT - 1) & 1;
#pragma unroll
        for (int mi = 0; mi < 8; ++mi) af[mi] = rdA(rd, mi, oK0);
#pragma unroll
        for (int ni = 0; ni < 4; ++ni) bfr[ni] = rdB(rd, ni, oK0);
        WAITLG(0);
#pragma unroll
        for (int mi = 0; mi < 8; ++mi)
#pragma unroll
            for (int ni = 0; ni < 4; ++ni)
                acc[mi][ni] = MFMA16(af[mi], bfr[ni], acc[mi][ni]);
#pragma unroll
        for (int mi = 0; mi < 8; ++mi) af[mi] = rdA(rd, mi, oK1);
#pragma unroll
        for (int ni = 0; ni < 4; ++ni) bfr[ni] = rdB(rd, ni, oK1);
        WAITLG(0);
#pragma unroll
        for (int mi = 0; mi < 8; ++mi)
#pragma unroll
            for (int ni = 0; ni < 4; ++ni)
                acc[mi][ni] = MFMA16(af[mi], bfr[ni], acc[mi][ni]);
    }

    // epilogue: acc layout col=lane&15, row=(lane>>4)*4+r (m89-verified)
#pragma unroll
    for (int ni = 0; ni < 4; ++ni) {
        const int gc = tn * BN + wn * 64 + ni * 16 + frow;
        const float bv = Bias[bidx * NDIM + gc];
#pragma unroll
        for (int mi = 0; mi < 8; ++mi) {
            const int gr0 = tm * BM + wm * 128 + mi * 16 + khi * 4;
            float* po = Out + ((size_t)bidx * MDIM + gr0) * NDIM + gc;
#pragma unroll
            for (int r = 0; r < 4; ++r)
                po[(size_t)r * NDIM] = acc[mi][ni][r] + bv;
        }
    }
}

extern "C" void kernel_launch(void* const* d_in, const int* in_sizes, int n_in,
                              void* d_out, int out_size, void* d_ws, size_t ws_size,
                              hipStream_t stream) {
    const float* X  = (const float*)d_in[0];
    const float* W  = (const float*)d_in[1];
    const float* Bs = (const float*)d_in[2];
    float* Out = (float*)d_out;

    grouped_fc_kernel<<<dim3(512), dim3(512), 0, stream>>>(X, W, Bs, Out);
}